// Round 11
// baseline (339.978 us; speedup 1.0000x reference)
//
#include <hip/hip_runtime.h>
#include <hip/hip_bf16.h>

// Problem constants (T=2048, B=32, N=1024, H=8, K=128, K2=16)
#define T_DIM 2048
#define B_DIM 32
#define N_DIM 1024
#define H_DIM 8
#define K_DIM 128
#define Q_DIM 16

typedef __bf16 bf16x8 __attribute__((ext_vector_type(8)));
typedef __bf16 bf16x4 __attribute__((ext_vector_type(4)));
typedef float  f32x4  __attribute__((ext_vector_type(4)));

__device__ inline bf16x8 cvt8(float4 a, float4 b) {
    bf16x8 r;
    r[0] = (__bf16)a.x; r[1] = (__bf16)a.y; r[2] = (__bf16)a.z; r[3] = (__bf16)a.w;
    r[4] = (__bf16)b.x; r[5] = (__bf16)b.y; r[6] = (__bf16)b.z; r[7] = (__bf16)b.w;
    return r;
}

// ---------------------------------------------------------------------------
// K0: f32 -> bf16 convert, 8 elems/thread.
// ---------------------------------------------------------------------------
__global__ __launch_bounds__(256)
void cvt_f32_bf16(const float* __restrict__ s, __bf16* __restrict__ d)
{
    const long i = ((long)blockIdx.x * 256 + threadIdx.x) * 8;
    float4 a = *(const float4*)(s + i);
    float4 b = *(const float4*)(s + i + 4);
    *(bf16x8*)(d + i) = cvt8(a, b);
}

// ---------------------------------------------------------------------------
// K1: R9 GEMM (unchanged — proven 182 us): 8-phase 256x256, bf16 A via
// global_load_lds, XOR-swizzled LDS, counted vmcnt(4), setprio, unroll-by-2,
// operand-swapped MFMA (transposed D), fused time-mean partials in epilogue.
// ---------------------------------------------------------------------------
__global__ __launch_bounds__(512, 1)
void gemm_x_8ph(const __bf16* __restrict__ A, const __bf16* __restrict__ Bw,
                const float* __restrict__ bias, __bf16* __restrict__ X,
                float* __restrict__ mpart)
{
    __shared__ __bf16 ldsA[2][16384];   // [slot][256 rows * 64 k]
    __shared__ __bf16 ldsB[2][16384];
    __bf16* ldsAf = &ldsA[0][0];
    __bf16* ldsBf = &ldsB[0][0];

    const int tid  = threadIdx.x;
    const int lane = tid & 63;
    const int w    = tid >> 6;     // 0..7
    const int wm   = w >> 2;       // 0..1 -> 128 rows
    const int wn   = w & 3;        // 0..3 -> 64 cols

    const int bid  = blockIdx.x;                    // 1024 blocks, %8==0
    const int wgid = (bid & 7) * 128 + (bid >> 3);  // bijective XCD swizzle
    const int bm   = wgid >> 2;                     // 0..255
    const int bn   = wgid & 3;                      // 0..3
    const long row0 = (long)bm * 256;
    const long col0 = (long)bn * 256;

    const int srow = w * 8 + (lane >> 3);
    const int scol = ((lane & 7) ^ (lane >> 3)) * 8;
    const __bf16* Ag = A  + (row0 + srow) * 1024 + scol;
    const __bf16* Bg = Bw + (col0 + srow) * 1024 + scol;
    const int ldst = w * 512;

    const int fr = lane & 15;
    const int g2 = lane >> 4;
    const int x7 = lane & 7;

    const __bf16* aK0 = ldsAf + (wm * 128 + fr) * 64 + ((g2    ) ^ x7) * 8;
    const __bf16* aK1 = ldsAf + (wm * 128 + fr) * 64 + ((4 + g2) ^ x7) * 8;
    const __bf16* bK0 = ldsBf + (wn * 64  + fr) * 64 + ((g2    ) ^ x7) * 8;
    const __bf16* bK1 = ldsBf + (wn * 64  + fr) * 64 + ((4 + g2) ^ x7) * 8;

    f32x4 acc[8][4];
    #pragma unroll
    for (int i = 0; i < 8; ++i)
        #pragma unroll
        for (int j = 0; j < 4; ++j)
            acc[i][j] = f32x4{0.f, 0.f, 0.f, 0.f};

    #define GLDA(SRC_, DST_) __builtin_amdgcn_global_load_lds( \
        (const __attribute__((address_space(1))) void*)(SRC_), \
        (__attribute__((address_space(3))) void*)(DST_), 16, 0, 0)

    // prologue: KT0.{A0,A1,B0,B1}, KT1.{B0,B1}
    #pragma unroll
    for (int j = 0; j < 2; ++j) GLDA(Ag + (long)j * 65536,          ldsAf + j * 4096 + ldst);
    #pragma unroll
    for (int j = 0; j < 2; ++j) GLDA(Ag + 131072 + (long)j * 65536, ldsAf + 8192 + j * 4096 + ldst);
    #pragma unroll
    for (int j = 0; j < 2; ++j) GLDA(Bg + (long)j * 65536,          ldsBf + j * 4096 + ldst);
    #pragma unroll
    for (int j = 0; j < 2; ++j) GLDA(Bg + 131072 + (long)j * 65536, ldsBf + 8192 + j * 4096 + ldst);
    #pragma unroll
    for (int j = 0; j < 2; ++j) GLDA(Bg + 64 + (long)j * 65536,          ldsBf + 16384 + j * 4096 + ldst);
    #pragma unroll
    for (int j = 0; j < 2; ++j) GLDA(Bg + 64 + 131072 + (long)j * 65536, ldsBf + 16384 + 8192 + j * 4096 + ldst);
    asm volatile("s_waitcnt vmcnt(4)" ::: "memory");
    __builtin_amdgcn_sched_barrier(0);
    __builtin_amdgcn_s_barrier();

    const __bf16* AgN = Ag + 64;
    const __bf16* BgN = Bg + 128;

    #define MFMA16(AF_, BF_, OFF_)                                             \
        __builtin_amdgcn_s_setprio(1);                                         \
        _Pragma("unroll") for (int mi = 0; mi < 4; ++mi)                       \
            _Pragma("unroll") for (int ni = 0; ni < 4; ++ni)                   \
                acc[mi + (OFF_)][ni] = __builtin_amdgcn_mfma_f32_16x16x32_bf16(\
                    BF_[ni], AF_[mi], acc[mi + (OFF_)][ni], 0, 0, 0);          \
        __builtin_amdgcn_s_setprio(0);

    #define LGKM0()                                                            \
        asm volatile("s_waitcnt lgkmcnt(0)" ::: "memory");                     \
        __builtin_amdgcn_sched_barrier(0);

    #define KTBODY(SO_, SN_, KO_, STGA_, STGB_, VM_)                           \
    {                                                                          \
        bf16x8 a0[4], b0[4], a0h[4], b1[4], a1[4], a1h[4];                     \
        _Pragma("unroll") for (int mi = 0; mi < 4; ++mi)                       \
            a0[mi] = *(const bf16x8*)(aK0 + (SO_) + mi * 1024);                \
        _Pragma("unroll") for (int ni = 0; ni < 4; ++ni)                       \
            b0[ni] = *(const bf16x8*)(bK0 + (SO_) + ni * 1024);                \
        if (STGA_) {                                                           \
            _Pragma("unroll") for (int j = 0; j < 2; ++j)                      \
                GLDA(AgN + (KO_) + (long)j * 65536,                            \
                     ldsAf + (SN_) + j * 4096 + ldst);                         \
        }                                                                      \
        __builtin_amdgcn_s_barrier();                                          \
        LGKM0();                                                               \
        MFMA16(a0, b0, 0);                                                     \
        __builtin_amdgcn_s_barrier();                                          \
        _Pragma("unroll") for (int mi = 0; mi < 4; ++mi)                       \
            a0h[mi] = *(const bf16x8*)(aK1 + (SO_) + mi * 1024);               \
        _Pragma("unroll") for (int ni = 0; ni < 4; ++ni)                       \
            b1[ni]  = *(const bf16x8*)(bK1 + (SO_) + ni * 1024);               \
        if (STGA_) {                                                           \
            _Pragma("unroll") for (int j = 0; j < 2; ++j)                      \
                GLDA(AgN + (KO_) + 131072 + (long)j * 65536,                   \
                     ldsAf + (SN_) + 8192 + j * 4096 + ldst);                  \
        }                                                                      \
        __builtin_amdgcn_s_barrier();                                          \
        LGKM0();                                                               \
        MFMA16(a0h, b1, 0);                                                    \
        __builtin_amdgcn_s_barrier();                                          \
        _Pragma("unroll") for (int mi = 0; mi < 4; ++mi)                       \
            a1[mi] = *(const bf16x8*)(aK0 + (SO_) + (mi + 4) * 1024);          \
        if (STGB_) {                                                           \
            _Pragma("unroll") for (int j = 0; j < 2; ++j)                      \
                GLDA(BgN + (KO_) + (long)j * 65536,                            \
                     ldsBf + (SO_) + j * 4096 + ldst);                         \
        }                                                                      \
        __builtin_amdgcn_s_barrier();                                          \
        LGKM0();                                                               \
        MFMA16(a1, b0, 4);                                                     \
        __builtin_amdgcn_s_barrier();                                          \
        _Pragma("unroll") for (int mi = 0; mi < 4; ++mi)                       \
            a1h[mi] = *(const bf16x8*)(aK1 + (SO_) + (mi + 4) * 1024);         \
        if (STGB_) {                                                           \
            _Pragma("unroll") for (int j = 0; j < 2; ++j)                      \
                GLDA(BgN + (KO_) + 131072 + (long)j * 65536,                   \
                     ldsBf + (SO_) + 8192 + j * 4096 + ldst);                  \
        }                                                                      \
        if ((VM_) == 4)      { asm volatile("s_waitcnt vmcnt(4)" ::: "memory"); } \
        else if ((VM_) == 0) { asm volatile("s_waitcnt vmcnt(0)" ::: "memory"); } \
        __builtin_amdgcn_sched_barrier(0);                                     \
        __builtin_amdgcn_s_barrier();                                          \
        LGKM0();                                                               \
        MFMA16(a1h, b1, 4);                                                    \
        __builtin_amdgcn_s_barrier();                                          \
    }

    #pragma unroll 1
    for (int ii = 0; ii < 7; ++ii) {       // KT 0..13
        KTBODY(0,     16384, 0,  1, 1, 4);
        KTBODY(16384, 0,     64, 1, 1, 4);
        AgN += 128; BgN += 128;
    }
    KTBODY(0,     16384, 0, 1, 0, 0);      // KT14: stage KT15.A, drain
    KTBODY(16384, 0,     0, 0, 0, -1);     // KT15: final
    #undef KTBODY
    #undef MFMA16
    #undef LGKM0
    #undef GLDA

    // epilogue: transposed D, bf16x4 stores + fused mean partials
    const int g4 = lane >> 4;
    const long colb = col0 + wn * 64 + g4 * 4;

    float4 bias4[4];
    #pragma unroll
    for (int ni = 0; ni < 4; ++ni)
        bias4[ni] = *(const float4*)(bias + colb + ni * 16);

    f32x4 msum[2][4];
    #pragma unroll
    for (int bh = 0; bh < 2; ++bh)
        #pragma unroll
        for (int ni = 0; ni < 4; ++ni)
            msum[bh][ni] = f32x4{0.f, 0.f, 0.f, 0.f};

    #pragma unroll
    for (int mi = 0; mi < 8; ++mi) {
        const long row = row0 + wm * 128 + mi * 16 + fr;
        #pragma unroll
        for (int ni = 0; ni < 4; ++ni) {
            f32x4 xv;
            xv[0] = acc[mi][ni][0] + bias4[ni].x;
            xv[1] = acc[mi][ni][1] + bias4[ni].y;
            xv[2] = acc[mi][ni][2] + bias4[ni].z;
            xv[3] = acc[mi][ni][3] + bias4[ni].w;
            bf16x4 xb;
            xb[0] = (__bf16)xv[0]; xb[1] = (__bf16)xv[1];
            xb[2] = (__bf16)xv[2]; xb[3] = (__bf16)xv[3];
            *(bf16x4*)(X + row * 1024 + colb + ni * 16) = xb;
            msum[mi & 1][ni] += xv;
        }
    }

    float* ldsf = (float*)ldsAf;
    __syncthreads();
    if (wm == 1) {
        #pragma unroll
        for (int bh = 0; bh < 2; ++bh)
            #pragma unroll
            for (int ni = 0; ni < 4; ++ni)
                *(f32x4*)(ldsf + (bh * 16 + fr) * 256 + wn * 64 + ni * 16 + g4 * 4) = msum[bh][ni];
    }
    __syncthreads();
    if (wm == 0) {
        #pragma unroll
        for (int bh = 0; bh < 2; ++bh) {
            const int b = bh * 16 + fr;
            #pragma unroll
            for (int ni = 0; ni < 4; ++ni) {
                f32x4 other = *(const f32x4*)(ldsf + b * 256 + wn * 64 + ni * 16 + g4 * 4);
                f32x4 tot = msum[bh][ni] + other;
                *(f32x4*)(mpart + ((long)bm * 32 + b) * 1024 + colb + ni * 16) = tot;
            }
        }
    }
}

// ---------------------------------------------------------------------------
// K3: finalize mean from fused partials, gate2[b,h,q] = tanh(m.Wm[q]+bWm[q]).
// ---------------------------------------------------------------------------
__global__ __launch_bounds__(256)
void gate2_k(const float* __restrict__ mpart, const float* __restrict__ Wm,
             const float* __restrict__ bWm, float* __restrict__ g2)
{
    __shared__ float mrow[1024];
    const int b = blockIdx.x;
    const int j4 = threadIdx.x * 4;
    f32x4 s = f32x4{0.f, 0.f, 0.f, 0.f};
    for (int bm = 0; bm < 256; ++bm)
        s += *(const f32x4*)(mpart + ((long)bm * 32 + b) * 1024 + j4);
    mrow[j4 + 0] = s[0] * (1.0f / 2048.0f);
    mrow[j4 + 1] = s[1] * (1.0f / 2048.0f);
    mrow[j4 + 2] = s[2] * (1.0f / 2048.0f);
    mrow[j4 + 3] = s[3] * (1.0f / 2048.0f);
    __syncthreads();
    if (threadIdx.x < 128) {
        const int h = threadIdx.x >> 4;
        const int q = threadIdx.x & 15;
        float d = bWm[q];
        #pragma unroll 8
        for (int k = 0; k < 128; ++k) d += mrow[h * 128 + k] * Wm[q * 128 + k];
        g2[(b * 8 + h) * 16 + q] = tanhf(d);
    }
}

// ---------------------------------------------------------------------------
// K4 (NEW): fused flash-style scores+softmax+weighted-sum, one block per
// (b,h). 32 chunks of 64 t: MFMA scores (scores_k pattern, bWh dropped —
// softmax shift-invariant) -> LDS; wave0: online max m, rescale f, p[64],
// running l; all threads rescale+accumulate c[k] from L1/L2-hot X rows.
// X read ONCE (128 MB); no sbuf/wpart; 4 launches -> 1.
// ---------------------------------------------------------------------------
__global__ __launch_bounds__(256)
void attn_k(const __bf16* __restrict__ X, const float* __restrict__ W,
            const float* __restrict__ bW, const float* __restrict__ g2,
            const float* __restrict__ Wh, float* __restrict__ out)
{
    __shared__ float sch[64];     // raw scores of current chunk
    __shared__ float pl[64];      // p = exp(s - m_new)
    __shared__ float red[1024];   // final 8x128 k-reduction
    __shared__ float scal[3];     // [0]=m, [1]=f, [2]=l

    const int tid  = threadIdx.x;
    const int lane = tid & 63;
    const int w    = tid >> 6;       // wave 0..3
    const int bh   = blockIdx.x;     // 0..255
    const int b    = bh >> 3;
    const int h    = bh & 7;
    const int q    = lane & 15;
    const int g4   = lane >> 4;

    if (tid == 0) { scal[0] = -1e30f; scal[1] = 0.f; scal[2] = 0.f; }

    // B-frag: W[q][k] f32 -> bf16, loaded once
    bf16x8 bfr[4];
    #pragma unroll
    for (int c = 0; c < 4; ++c) {
        const float* wp = W + q * 128 + c * 32 + g4 * 8;
        float4 w0 = *(const float4*)wp;
        float4 w1 = *(const float4*)(wp + 4);
        bfr[c] = cvt8(w0, w1);
    }
    const float whq = Wh[q];
    const float bWv = bW[q];
    const float gq  = g2[(b * 8 + h) * 16 + q];

    // per-wave A source: t = tbase + w*16 + q
    const __bf16* xp = X + ((long)(w * 16 + q) * 32 + b) * 1024 + h * 128 + g4 * 8;
    // accumulation source: thread (tr, kq) reads t = tbase + tr + 8*i, k = kq*4
    const int tr = tid >> 5;
    const int kq = tid & 31;
    const __bf16* xa = X + ((long)tr * 32 + b) * 1024 + h * 128 + kq * 4;

    float c0 = 0.f, c1 = 0.f, c2 = 0.f, c3 = 0.f;

    __syncthreads();   // scal init visible

    #pragma unroll 1
    for (int ch = 0; ch < 32; ++ch) {
        // ---- phase 1: scores for 64 t (wave w -> t = ch*64 + w*16 + 0..15)
        bf16x8 afr[4];
        #pragma unroll
        for (int c = 0; c < 4; ++c) afr[c] = *(const bf16x8*)(xp + c * 32);
        f32x4 acc = f32x4{0.f, 0.f, 0.f, 0.f};
        #pragma unroll
        for (int c = 0; c < 4; ++c)
            acc = __builtin_amdgcn_mfma_f32_16x16x32_bf16(afr[c], bfr[c], acc, 0, 0, 0);
        #pragma unroll
        for (int r = 0; r < 4; ++r) {
            float val = tanhf(acc[r] + bWv) * gq * whq;
            val += __shfl_xor(val, 1);
            val += __shfl_xor(val, 2);
            val += __shfl_xor(val, 4);
            val += __shfl_xor(val, 8);
            if (q == 0) sch[w * 16 + g4 * 4 + r] = val;
        }
        __syncthreads();   // B0: sch visible

        // ---- phase 2: wave0 updates m, f, p[], l
        if (tid < 64) {
            float v = sch[tid];
            float mx = v;
            #pragma unroll
            for (int off = 1; off < 64; off <<= 1)
                mx = fmaxf(mx, __shfl_xor(mx, off));
            const float mold = scal[0];
            const float newm = fmaxf(mold, mx);
            const float f    = __expf(mold - newm);
            const float p    = __expf(v - newm);
            pl[tid] = p;
            float ps = p;
            #pragma unroll
            for (int off = 1; off < 64; off <<= 1)
                ps += __shfl_xor(ps, off);
            if (tid == 0) {
                scal[0] = newm;
                scal[1] = f;
                scal[2] = scal[2] * f + ps;
            }
        }
        __syncthreads();   // B1: pl, scal visible

        // ---- phase 3: rescale + accumulate 8 t's per thread (X rows L2-hot)
        const float f = scal[1];
        if (f != 1.0f) { c0 *= f; c1 *= f; c2 *= f; c3 *= f; }
        #pragma unroll
        for (int i = 0; i < 8; ++i) {
            const float p = pl[tr + 8 * i];
            bf16x4 xv = *(const bf16x4*)(xa + (long)(8 * i) * 32768);
            c0 += p * (float)xv[0];
            c1 += p * (float)xv[1];
            c2 += p * (float)xv[2];
            c3 += p * (float)xv[3];
        }
        __syncthreads();   // B2: pl/sch reads done before next overwrite

        xp += 64 * 32768;
        xa += 64 * 32768;
    }

    // ---- final: reduce 8 tr-partials per k, divide by l
    red[tr * 128 + kq * 4 + 0] = c0;
    red[tr * 128 + kq * 4 + 1] = c1;
    red[tr * 128 + kq * 4 + 2] = c2;
    red[tr * 128 + kq * 4 + 3] = c3;
    __syncthreads();
    if (tid < 128) {
        float s = 0.f;
        #pragma unroll
        for (int r = 0; r < 8; ++r) s += red[r * 128 + tid];
        out[b * 1024 + h * 128 + tid] = s / scal[2];
    }
}

extern "C" void kernel_launch(void* const* d_in, const int* in_sizes, int n_in,
                              void* d_out, int out_size, void* d_ws, size_t ws_size,
                              hipStream_t stream)
{
    const float* hyp = (const float*)d_in[0];
    const float* Wmh = (const float*)d_in[1];
    const float* bmh = (const float*)d_in[2];
    const float* W   = (const float*)d_in[3];
    const float* bW  = (const float*)d_in[4];
    const float* Wm  = (const float*)d_in[5];
    const float* bWm = (const float*)d_in[6];
    const float* Wh  = (const float*)d_in[7];
    float* out = (float*)d_out;

    char* ws = (char*)d_ws;
    const size_t SZ_X   = 134217728;   // X bf16 (65536 x 1024)
    const size_t SZ_AB  = 134217728;   // Ab bf16 hyp
    const size_t SZ_BB  = 2097152;     // Bb bf16 Wmh
    const size_t SZ_MP  = 33554432;    // mpart f32 (256 x 32 x 1024)
    const size_t SZ_G2  = 16384;

    size_t off = 0;
    __bf16* X     = (__bf16*)(ws + off); off += SZ_X;
    __bf16* Ab    = (__bf16*)(ws + off); off += SZ_AB;
    __bf16* Bb    = (__bf16*)(ws + off); off += SZ_BB;
    float*  mpart = (float*) (ws + off); off += SZ_MP;
    float*  g2    = (float*) (ws + off); off += SZ_G2;

    cvt_f32_bf16<<<32768, 256, 0, stream>>>(hyp, Ab);
    cvt_f32_bf16<<<512,   256, 0, stream>>>(Wmh, Bb);
    gemm_x_8ph<<<1024, 512, 0, stream>>>(Ab, Bb, bmh, X, mpart);
    gate2_k<<<32, 256, 0, stream>>>(mpart, Wm, bWm, g2);
    attn_k<<<256, 256, 0, stream>>>(X, W, bW, g2, Wh, out);
}

// Round 12
// 298.750 us; speedup vs baseline: 1.1380x; 1.1380x over previous
//
#include <hip/hip_runtime.h>
#include <hip/hip_bf16.h>

// Problem constants (T=2048, B=32, N=1024, H=8, K=128, K2=16)
#define T_DIM 2048
#define B_DIM 32
#define N_DIM 1024
#define H_DIM 8
#define K_DIM 128
#define Q_DIM 16

typedef __bf16 bf16x8 __attribute__((ext_vector_type(8)));
typedef __bf16 bf16x4 __attribute__((ext_vector_type(4)));
typedef float  f32x4  __attribute__((ext_vector_type(4)));

__device__ inline bf16x8 cvt8(float4 a, float4 b) {
    bf16x8 r;
    r[0] = (__bf16)a.x; r[1] = (__bf16)a.y; r[2] = (__bf16)a.z; r[3] = (__bf16)a.w;
    r[4] = (__bf16)b.x; r[5] = (__bf16)b.y; r[6] = (__bf16)b.z; r[7] = (__bf16)b.w;
    return r;
}

// ---------------------------------------------------------------------------
// K0: f32 -> bf16 convert, 8 elems/thread.
// ---------------------------------------------------------------------------
__global__ __launch_bounds__(256)
void cvt_f32_bf16(const float* __restrict__ s, __bf16* __restrict__ d)
{
    const long i = ((long)blockIdx.x * 256 + threadIdx.x) * 8;
    float4 a = *(const float4*)(s + i);
    float4 b = *(const float4*)(s + i + 4);
    *(bf16x8*)(d + i) = cvt8(a, b);
}

// ---------------------------------------------------------------------------
// K1: R9 GEMM (proven 181 us): 8-phase 256x256, bf16 A via global_load_lds,
// XOR-swizzled LDS, counted vmcnt(4), setprio, unroll-by-2, operand-swapped
// MFMA (transposed D), fused time-mean partials in epilogue.
// ---------------------------------------------------------------------------
__global__ __launch_bounds__(512, 1)
void gemm_x_8ph(const __bf16* __restrict__ A, const __bf16* __restrict__ Bw,
                const float* __restrict__ bias, __bf16* __restrict__ X,
                float* __restrict__ mpart)
{
    __shared__ __bf16 ldsA[2][16384];   // [slot][256 rows * 64 k]
    __shared__ __bf16 ldsB[2][16384];
    __bf16* ldsAf = &ldsA[0][0];
    __bf16* ldsBf = &ldsB[0][0];

    const int tid  = threadIdx.x;
    const int lane = tid & 63;
    const int w    = tid >> 6;     // 0..7
    const int wm   = w >> 2;       // 0..1 -> 128 rows
    const int wn   = w & 3;        // 0..3 -> 64 cols

    const int bid  = blockIdx.x;                    // 1024 blocks, %8==0
    const int wgid = (bid & 7) * 128 + (bid >> 3);  // bijective XCD swizzle
    const int bm   = wgid >> 2;                     // 0..255
    const int bn   = wgid & 3;                      // 0..3
    const long row0 = (long)bm * 256;
    const long col0 = (long)bn * 256;

    const int srow = w * 8 + (lane >> 3);
    const int scol = ((lane & 7) ^ (lane >> 3)) * 8;
    const __bf16* Ag = A  + (row0 + srow) * 1024 + scol;
    const __bf16* Bg = Bw + (col0 + srow) * 1024 + scol;
    const int ldst = w * 512;

    const int fr = lane & 15;
    const int g2 = lane >> 4;
    const int x7 = lane & 7;

    const __bf16* aK0 = ldsAf + (wm * 128 + fr) * 64 + ((g2    ) ^ x7) * 8;
    const __bf16* aK1 = ldsAf + (wm * 128 + fr) * 64 + ((4 + g2) ^ x7) * 8;
    const __bf16* bK0 = ldsBf + (wn * 64  + fr) * 64 + ((g2    ) ^ x7) * 8;
    const __bf16* bK1 = ldsBf + (wn * 64  + fr) * 64 + ((4 + g2) ^ x7) * 8;

    f32x4 acc[8][4];
    #pragma unroll
    for (int i = 0; i < 8; ++i)
        #pragma unroll
        for (int j = 0; j < 4; ++j)
            acc[i][j] = f32x4{0.f, 0.f, 0.f, 0.f};

    #define GLDA(SRC_, DST_) __builtin_amdgcn_global_load_lds( \
        (const __attribute__((address_space(1))) void*)(SRC_), \
        (__attribute__((address_space(3))) void*)(DST_), 16, 0, 0)

    // prologue: KT0.{A0,A1,B0,B1}, KT1.{B0,B1}
    #pragma unroll
    for (int j = 0; j < 2; ++j) GLDA(Ag + (long)j * 65536,          ldsAf + j * 4096 + ldst);
    #pragma unroll
    for (int j = 0; j < 2; ++j) GLDA(Ag + 131072 + (long)j * 65536, ldsAf + 8192 + j * 4096 + ldst);
    #pragma unroll
    for (int j = 0; j < 2; ++j) GLDA(Bg + (long)j * 65536,          ldsBf + j * 4096 + ldst);
    #pragma unroll
    for (int j = 0; j < 2; ++j) GLDA(Bg + 131072 + (long)j * 65536, ldsBf + 8192 + j * 4096 + ldst);
    #pragma unroll
    for (int j = 0; j < 2; ++j) GLDA(Bg + 64 + (long)j * 65536,          ldsBf + 16384 + j * 4096 + ldst);
    #pragma unroll
    for (int j = 0; j < 2; ++j) GLDA(Bg + 64 + 131072 + (long)j * 65536, ldsBf + 16384 + 8192 + j * 4096 + ldst);
    asm volatile("s_waitcnt vmcnt(4)" ::: "memory");
    __builtin_amdgcn_sched_barrier(0);
    __builtin_amdgcn_s_barrier();

    const __bf16* AgN = Ag + 64;
    const __bf16* BgN = Bg + 128;

    #define MFMA16(AF_, BF_, OFF_)                                             \
        __builtin_amdgcn_s_setprio(1);                                         \
        _Pragma("unroll") for (int mi = 0; mi < 4; ++mi)                       \
            _Pragma("unroll") for (int ni = 0; ni < 4; ++ni)                   \
                acc[mi + (OFF_)][ni] = __builtin_amdgcn_mfma_f32_16x16x32_bf16(\
                    BF_[ni], AF_[mi], acc[mi + (OFF_)][ni], 0, 0, 0);          \
        __builtin_amdgcn_s_setprio(0);

    #define LGKM0()                                                            \
        asm volatile("s_waitcnt lgkmcnt(0)" ::: "memory");                     \
        __builtin_amdgcn_sched_barrier(0);

    #define KTBODY(SO_, SN_, KO_, STGA_, STGB_, VM_)                           \
    {                                                                          \
        bf16x8 a0[4], b0[4], a0h[4], b1[4], a1[4], a1h[4];                     \
        _Pragma("unroll") for (int mi = 0; mi < 4; ++mi)                       \
            a0[mi] = *(const bf16x8*)(aK0 + (SO_) + mi * 1024);                \
        _Pragma("unroll") for (int ni = 0; ni < 4; ++ni)                       \
            b0[ni] = *(const bf16x8*)(bK0 + (SO_) + ni * 1024);                \
        if (STGA_) {                                                           \
            _Pragma("unroll") for (int j = 0; j < 2; ++j)                      \
                GLDA(AgN + (KO_) + (long)j * 65536,                            \
                     ldsAf + (SN_) + j * 4096 + ldst);                         \
        }                                                                      \
        __builtin_amdgcn_s_barrier();                                          \
        LGKM0();                                                               \
        MFMA16(a0, b0, 0);                                                     \
        __builtin_amdgcn_s_barrier();                                          \
        _Pragma("unroll") for (int mi = 0; mi < 4; ++mi)                       \
            a0h[mi] = *(const bf16x8*)(aK1 + (SO_) + mi * 1024);               \
        _Pragma("unroll") for (int ni = 0; ni < 4; ++ni)                       \
            b1[ni]  = *(const bf16x8*)(bK1 + (SO_) + ni * 1024);               \
        if (STGA_) {                                                           \
            _Pragma("unroll") for (int j = 0; j < 2; ++j)                      \
                GLDA(AgN + (KO_) + 131072 + (long)j * 65536,                   \
                     ldsAf + (SN_) + 8192 + j * 4096 + ldst);                  \
        }                                                                      \
        __builtin_amdgcn_s_barrier();                                          \
        LGKM0();                                                               \
        MFMA16(a0h, b1, 0);                                                    \
        __builtin_amdgcn_s_barrier();                                          \
        _Pragma("unroll") for (int mi = 0; mi < 4; ++mi)                       \
            a1[mi] = *(const bf16x8*)(aK0 + (SO_) + (mi + 4) * 1024);          \
        if (STGB_) {                                                           \
            _Pragma("unroll") for (int j = 0; j < 2; ++j)                      \
                GLDA(BgN + (KO_) + (long)j * 65536,                            \
                     ldsBf + (SO_) + j * 4096 + ldst);                         \
        }                                                                      \
        __builtin_amdgcn_s_barrier();                                          \
        LGKM0();                                                               \
        MFMA16(a1, b0, 4);                                                     \
        __builtin_amdgcn_s_barrier();                                          \
        _Pragma("unroll") for (int mi = 0; mi < 4; ++mi)                       \
            a1h[mi] = *(const bf16x8*)(aK1 + (SO_) + (mi + 4) * 1024);         \
        if (STGB_) {                                                           \
            _Pragma("unroll") for (int j = 0; j < 2; ++j)                      \
                GLDA(BgN + (KO_) + 131072 + (long)j * 65536,                   \
                     ldsBf + (SO_) + 8192 + j * 4096 + ldst);                  \
        }                                                                      \
        if ((VM_) == 4)      { asm volatile("s_waitcnt vmcnt(4)" ::: "memory"); } \
        else if ((VM_) == 0) { asm volatile("s_waitcnt vmcnt(0)" ::: "memory"); } \
        __builtin_amdgcn_sched_barrier(0);                                     \
        __builtin_amdgcn_s_barrier();                                          \
        LGKM0();                                                               \
        MFMA16(a1h, b1, 4);                                                    \
        __builtin_amdgcn_s_barrier();                                          \
    }

    #pragma unroll 1
    for (int ii = 0; ii < 7; ++ii) {       // KT 0..13
        KTBODY(0,     16384, 0,  1, 1, 4);
        KTBODY(16384, 0,     64, 1, 1, 4);
        AgN += 128; BgN += 128;
    }
    KTBODY(0,     16384, 0, 1, 0, 0);      // KT14: stage KT15.A, drain
    KTBODY(16384, 0,     0, 0, 0, -1);     // KT15: final
    #undef KTBODY
    #undef MFMA16
    #undef LGKM0
    #undef GLDA

    // epilogue: transposed D, bf16x4 stores + fused mean partials
    const int g4 = lane >> 4;
    const long colb = col0 + wn * 64 + g4 * 4;

    float4 bias4[4];
    #pragma unroll
    for (int ni = 0; ni < 4; ++ni)
        bias4[ni] = *(const float4*)(bias + colb + ni * 16);

    f32x4 msum[2][4];
    #pragma unroll
    for (int bh = 0; bh < 2; ++bh)
        #pragma unroll
        for (int ni = 0; ni < 4; ++ni)
            msum[bh][ni] = f32x4{0.f, 0.f, 0.f, 0.f};

    #pragma unroll
    for (int mi = 0; mi < 8; ++mi) {
        const long row = row0 + wm * 128 + mi * 16 + fr;
        #pragma unroll
        for (int ni = 0; ni < 4; ++ni) {
            f32x4 xv;
            xv[0] = acc[mi][ni][0] + bias4[ni].x;
            xv[1] = acc[mi][ni][1] + bias4[ni].y;
            xv[2] = acc[mi][ni][2] + bias4[ni].z;
            xv[3] = acc[mi][ni][3] + bias4[ni].w;
            bf16x4 xb;
            xb[0] = (__bf16)xv[0]; xb[1] = (__bf16)xv[1];
            xb[2] = (__bf16)xv[2]; xb[3] = (__bf16)xv[3];
            *(bf16x4*)(X + row * 1024 + colb + ni * 16) = xb;
            msum[mi & 1][ni] += xv;
        }
    }

    float* ldsf = (float*)ldsAf;
    __syncthreads();
    if (wm == 1) {
        #pragma unroll
        for (int bh = 0; bh < 2; ++bh)
            #pragma unroll
            for (int ni = 0; ni < 4; ++ni)
                *(f32x4*)(ldsf + (bh * 16 + fr) * 256 + wn * 64 + ni * 16 + g4 * 4) = msum[bh][ni];
    }
    __syncthreads();
    if (wm == 0) {
        #pragma unroll
        for (int bh = 0; bh < 2; ++bh) {
            const int b = bh * 16 + fr;
            #pragma unroll
            for (int ni = 0; ni < 4; ++ni) {
                f32x4 other = *(const f32x4*)(ldsf + b * 256 + wn * 64 + ni * 16 + g4 * 4);
                f32x4 tot = msum[bh][ni] + other;
                *(f32x4*)(mpart + ((long)bm * 32 + b) * 1024 + colb + ni * 16) = tot;
            }
        }
    }
}

// ---------------------------------------------------------------------------
// K3: finalize mean from fused partials, gate2[b,h,q] = tanh(m.Wm[q]+bWm[q]).
// ---------------------------------------------------------------------------
__global__ __launch_bounds__(256)
void gate2_k(const float* __restrict__ mpart, const float* __restrict__ Wm,
             const float* __restrict__ bWm, float* __restrict__ g2)
{
    __shared__ float mrow[1024];
    const int b = blockIdx.x;
    const int j4 = threadIdx.x * 4;
    f32x4 s = f32x4{0.f, 0.f, 0.f, 0.f};
    for (int bm = 0; bm < 256; ++bm)
        s += *(const f32x4*)(mpart + ((long)bm * 32 + b) * 1024 + j4);
    mrow[j4 + 0] = s[0] * (1.0f / 2048.0f);
    mrow[j4 + 1] = s[1] * (1.0f / 2048.0f);
    mrow[j4 + 2] = s[2] * (1.0f / 2048.0f);
    mrow[j4 + 3] = s[3] * (1.0f / 2048.0f);
    __syncthreads();
    if (threadIdx.x < 128) {
        const int h = threadIdx.x >> 4;
        const int q = threadIdx.x & 15;
        float d = bWm[q];
        #pragma unroll 8
        for (int k = 0; k < 128; ++k) d += mrow[h * 128 + k] * Wm[q * 128 + k];
        g2[(b * 8 + h) * 16 + q] = tanhf(d);
    }
}

// ---------------------------------------------------------------------------
// K4: flash-style partial pass. Block = (tc 0..7, bh 0..255), bh fastest
// (consecutive blocks read contiguous X rows). Each block: 256 t's in 4
// chunks of 64 -> partial (m, l, c[128]). 2048 blocks = 8/CU, so the
// 3-barrier chunk pipeline overlaps across blocks (R11's 1-block/CU flaw).
// ---------------------------------------------------------------------------
__global__ __launch_bounds__(256)
void attn_part(const __bf16* __restrict__ X, const float* __restrict__ W,
               const float* __restrict__ bW, const float* __restrict__ g2,
               const float* __restrict__ Wh,
               float* __restrict__ partC, float* __restrict__ partML)
{
    __shared__ float sch[64];
    __shared__ float pl[64];
    __shared__ float red[1024];
    __shared__ float scal[3];     // m, f, l

    const int tid  = threadIdx.x;
    const int lane = tid & 63;
    const int w    = tid >> 6;
    const int bx   = blockIdx.x;
    const int bh   = bx & 255;
    const int tc   = bx >> 8;      // 0..7
    const int b    = bh >> 3;
    const int h    = bh & 7;
    const int q    = lane & 15;
    const int g4   = lane >> 4;

    if (tid == 0) { scal[0] = -1e30f; scal[1] = 0.f; scal[2] = 0.f; }

    bf16x8 bfr[4];
    #pragma unroll
    for (int c = 0; c < 4; ++c) {
        const float* wp = W + q * 128 + c * 32 + g4 * 8;
        float4 w0 = *(const float4*)wp;
        float4 w1 = *(const float4*)(wp + 4);
        bfr[c] = cvt8(w0, w1);
    }
    const float whq = Wh[q];
    const float bWv = bW[q];
    const float gq  = g2[(b * 8 + h) * 16 + q];

    const long t0 = (long)tc * 256;
    const __bf16* xp = X + ((t0 + w * 16 + q) * 32 + b) * 1024 + h * 128 + g4 * 8;
    const int tr = tid >> 5;
    const int kq = tid & 31;
    const __bf16* xa = X + ((t0 + tr) * 32 + b) * 1024 + h * 128 + kq * 4;

    float c0 = 0.f, c1 = 0.f, c2 = 0.f, c3 = 0.f;

    __syncthreads();

    #pragma unroll 1
    for (int ch = 0; ch < 4; ++ch) {
        // phase 1: scores for 64 t
        bf16x8 afr[4];
        #pragma unroll
        for (int c = 0; c < 4; ++c) afr[c] = *(const bf16x8*)(xp + c * 32);
        f32x4 acc = f32x4{0.f, 0.f, 0.f, 0.f};
        #pragma unroll
        for (int c = 0; c < 4; ++c)
            acc = __builtin_amdgcn_mfma_f32_16x16x32_bf16(afr[c], bfr[c], acc, 0, 0, 0);
        #pragma unroll
        for (int r = 0; r < 4; ++r) {
            float val = tanhf(acc[r] + bWv) * gq * whq;
            val += __shfl_xor(val, 1);
            val += __shfl_xor(val, 2);
            val += __shfl_xor(val, 4);
            val += __shfl_xor(val, 8);
            if (q == 0) sch[w * 16 + g4 * 4 + r] = val;
        }
        __syncthreads();

        // phase 2: wave0 online-softmax update
        if (tid < 64) {
            float v = sch[tid];
            float mx = v;
            #pragma unroll
            for (int off = 1; off < 64; off <<= 1)
                mx = fmaxf(mx, __shfl_xor(mx, off));
            const float mold = scal[0];
            const float newm = fmaxf(mold, mx);
            const float f    = __expf(mold - newm);
            const float p    = __expf(v - newm);
            pl[tid] = p;
            float ps = p;
            #pragma unroll
            for (int off = 1; off < 64; off <<= 1)
                ps += __shfl_xor(ps, off);
            if (tid == 0) {
                scal[0] = newm;
                scal[1] = f;
                scal[2] = scal[2] * f + ps;
            }
        }
        __syncthreads();

        // phase 3: rescale + accumulate 8 t's/thread (rows L1/L2-hot)
        const float f = scal[1];
        if (f != 1.0f) { c0 *= f; c1 *= f; c2 *= f; c3 *= f; }
        #pragma unroll
        for (int i = 0; i < 8; ++i) {
            const float p = pl[tr + 8 * i];
            bf16x4 xv = *(const bf16x4*)(xa + (long)(8 * i) * 32768);
            c0 += p * (float)xv[0];
            c1 += p * (float)xv[1];
            c2 += p * (float)xv[2];
            c3 += p * (float)xv[3];
        }
        __syncthreads();

        xp += 64 * 32768;
        xa += 64 * 32768;
    }

    // reduce 8 tr-partials per k; store partial c, m, l
    red[tr * 128 + kq * 4 + 0] = c0;
    red[tr * 128 + kq * 4 + 1] = c1;
    red[tr * 128 + kq * 4 + 2] = c2;
    red[tr * 128 + kq * 4 + 3] = c3;
    __syncthreads();
    if (tid < 128) {
        float s = 0.f;
        #pragma unroll
        for (int r = 0; r < 8; ++r) s += red[r * 128 + tid];
        partC[((long)bh * 8 + tc) * 128 + tid] = s;
    }
    if (tid == 0) {
        partML[(bh * 8 + tc) * 2 + 0] = scal[0];
        partML[(bh * 8 + tc) * 2 + 1] = scal[2];
    }
}

// ---------------------------------------------------------------------------
// K5: merge 8 online-softmax partials per (b,h). 256 blocks x 128 threads.
// ---------------------------------------------------------------------------
__global__ __launch_bounds__(128)
void attn_merge(const float* __restrict__ partC, const float* __restrict__ partML,
                float* __restrict__ out)
{
    __shared__ float wgt[8];
    __shared__ float lsum;
    const int bh = blockIdx.x;
    const int k  = threadIdx.x;
    if (k == 0) {
        float m = -1e30f;
        #pragma unroll
        for (int tc = 0; tc < 8; ++tc) m = fmaxf(m, partML[(bh * 8 + tc) * 2]);
        float l = 0.f;
        #pragma unroll
        for (int tc = 0; tc < 8; ++tc) {
            float e = __expf(partML[(bh * 8 + tc) * 2] - m);
            wgt[tc] = e;
            l += partML[(bh * 8 + tc) * 2 + 1] * e;
        }
        lsum = l;
    }
    __syncthreads();
    float s = 0.f;
    #pragma unroll
    for (int tc = 0; tc < 8; ++tc)
        s += partC[((long)bh * 8 + tc) * 128 + k] * wgt[tc];
    const int b = bh >> 3;
    const int h = bh & 7;
    out[b * 1024 + h * 128 + k] = s / lsum;
}

extern "C" void kernel_launch(void* const* d_in, const int* in_sizes, int n_in,
                              void* d_out, int out_size, void* d_ws, size_t ws_size,
                              hipStream_t stream)
{
    const float* hyp = (const float*)d_in[0];
    const float* Wmh = (const float*)d_in[1];
    const float* bmh = (const float*)d_in[2];
    const float* W   = (const float*)d_in[3];
    const float* bW  = (const float*)d_in[4];
    const float* Wm  = (const float*)d_in[5];
    const float* bWm = (const float*)d_in[6];
    const float* Wh  = (const float*)d_in[7];
    float* out = (float*)d_out;

    char* ws = (char*)d_ws;
    const size_t SZ_X   = 134217728;   // X bf16 (65536 x 1024)
    const size_t SZ_AB  = 134217728;   // Ab bf16 hyp
    const size_t SZ_BB  = 2097152;     // Bb bf16 Wmh
    const size_t SZ_MP  = 33554432;    // mpart f32
    const size_t SZ_G2  = 16384;
    const size_t SZ_PC  = 1048576;     // partC f32 (2048 x 128)
    const size_t SZ_PM  = 16384;       // partML f32 (2048 x 2)

    size_t off = 0;
    __bf16* X      = (__bf16*)(ws + off); off += SZ_X;
    __bf16* Ab     = (__bf16*)(ws + off); off += SZ_AB;
    __bf16* Bb     = (__bf16*)(ws + off); off += SZ_BB;
    float*  mpart  = (float*) (ws + off); off += SZ_MP;
    float*  g2     = (float*) (ws + off); off += SZ_G2;
    float*  partC  = (float*) (ws + off); off += SZ_PC;
    float*  partML = (float*) (ws + off); off += SZ_PM;

    cvt_f32_bf16<<<32768, 256, 0, stream>>>(hyp, Ab);
    cvt_f32_bf16<<<512,   256, 0, stream>>>(Wmh, Bb);
    gemm_x_8ph<<<1024, 512, 0, stream>>>(Ab, Bb, bmh, X, mpart);
    gate2_k<<<32, 256, 0, stream>>>(mpart, Wm, bWm, g2);
    attn_part<<<2048, 256, 0, stream>>>(X, W, bW, g2, Wh, partC, partML);
    attn_merge<<<256, 128, 0, stream>>>(partC, partML, out);
}